// Round 7
// baseline (115.551 us; speedup 1.0000x reference)
//
#include <hip/hip_runtime.h>
#include <math.h>

typedef __attribute__((ext_vector_type(8))) short bf16x8;
typedef __attribute__((ext_vector_type(4))) float f32x4;

#define MFMA __builtin_amdgcn_mfma_f32_16x16x32_bf16

static __device__ __forceinline__ unsigned short f2bf(float f) {
  union { float f; unsigned u; } a; a.f = f;
  unsigned u = a.u;
  unsigned r = u + 0x7FFF + ((u >> 16) & 1);   // RNE
  return (unsigned short)(r >> 16);
}
static __device__ __forceinline__ float bf2f(unsigned short h) {
  union { unsigned u; float f; } a; a.u = ((unsigned)h) << 16;
  return a.f;
}
static __device__ __forceinline__ float tanh_fast(float x) {
  float ax = fabsf(x);
  float e = __expf(-2.0f * ax);
  float t = (1.0f - e) / (1.0f + e);
  t = (ax > 10.0f) ? 1.0f : t;
  return (x < 0.0f) ? -t : t;
}

// byte address in a [32][256]-bf16 plane with XOR swizzle (verified pattern)
#define AXB(row, cb) (((unsigned)((row) * 512 + (cb))) ^ ((((unsigned)(row)) & 7u) << 4))

// Weight transpose+split (blocks: W1 0..63, W2 64..127, Wv 128..143). Verified r6 code.
__global__ __launch_bounds__(256) void k_split(
    const float* __restrict__ W1, const float* __restrict__ W2, const float* __restrict__ Wv,
    unsigned short* __restrict__ W1Th, unsigned short* __restrict__ W1Tl,
    unsigned short* __restrict__ W2Th, unsigned short* __restrict__ W2Tl,
    unsigned short* __restrict__ WvTh, unsigned short* __restrict__ WvTl)
{
  const int b = blockIdx.x, t = threadIdx.x;
  __shared__ unsigned short shh[64 * 72], shl[64 * 72];
  const float* W; unsigned short *Th, *Tl; int Kd, Nd, k0, n0;
  if (b < 64)       { W = W1; Th = W1Th; Tl = W1Tl; Kd = 256;  Nd = 1024; k0 = (b & 3) * 64;         n0 = (b >> 2) * 64; }
  else if (b < 128) { W = W2; Th = W2Th; Tl = W2Tl; Kd = 1024; Nd = 256;  k0 = ((b - 64) & 15) * 64; n0 = ((b - 64) >> 4) * 64; }
  else              { W = Wv; Th = WvTh; Tl = WvTl; Kd = 256;  Nd = 256;  k0 = ((b - 128) & 3) * 64; n0 = ((b - 128) >> 2) * 64; }

  const int kloc = t >> 4, n4 = t & 15;
#pragma unroll
  for (int p = 0; p < 4; ++p) {
    const int kk = p * 16 + kloc;
    const float4 v = *reinterpret_cast<const float4*>(&W[(size_t)(k0 + kk) * Nd + n0 + n4 * 4]);
    const float vv[4] = {v.x, v.y, v.z, v.w};
#pragma unroll
    for (int e = 0; e < 4; ++e) {
      const unsigned short hh = f2bf(vv[e]);
      shh[(n4 * 4 + e) * 72 + kk] = hh;
      shl[(n4 * 4 + e) * 72 + kk] = f2bf(vv[e] - bf2f(hh));
    }
  }
  __syncthreads();
  const int nl = t >> 2, ko = (t & 3) * 16;
  const size_t dst = (size_t)(n0 + nl) * Kd + k0 + ko;
  *reinterpret_cast<uint4*>(&Th[dst])     = *reinterpret_cast<const uint4*>(&shh[nl * 72 + ko]);
  *reinterpret_cast<uint4*>(&Th[dst + 8]) = *reinterpret_cast<const uint4*>(&shh[nl * 72 + ko + 8]);
  *reinterpret_cast<uint4*>(&Tl[dst])     = *reinterpret_cast<const uint4*>(&shl[nl * 72 + ko]);
  *reinterpret_cast<uint4*>(&Tl[dst + 8]) = *reinterpret_cast<const uint4*>(&shl[nl * 72 + ko + 8]);
}

// Fully fused: per block = 32 sample rows.
//   H = tanh(x@W1+b1) in 32-col chunks (LDS only), out = H@W2+b2+x,
//   V(x),V(f) via MFMA, closed-form alpha, scaled store.
__global__ __launch_bounds__(256, 1) void k_fused(
    const float* __restrict__ X, const float* __restrict__ pb1, const float* __restrict__ pb2,
    const unsigned short* __restrict__ W1Th, const unsigned short* __restrict__ W1Tl,
    const unsigned short* __restrict__ W2Th, const unsigned short* __restrict__ W2Tl,
    const unsigned short* __restrict__ WvTh, const unsigned short* __restrict__ WvTl,
    float* __restrict__ OUT)
{
  __shared__ __align__(16) unsigned char smem[112896];
  unsigned char* XH_  = smem;            // [32][256] bf16, XOR swz
  unsigned char* XL_  = smem + 16384;
  unsigned char* B1H_ = smem + 32768;    // [32 hcol][256 k] XOR swz; later reused as FH
  unsigned char* B1L_ = smem + 49152;    // later FL
  unsigned char* B2H_ = smem + 65536;    // [256 col][pitch 40] bf16 (32 k used)
  unsigned char* B2L_ = smem + 86016;
  unsigned char* HCH_ = smem + 106496;   // [32][pitch 40]
  unsigned char* HCL_ = smem + 109056;
  float* PART = (float*)(smem + 111616); // [2][32][4]
  float* ALS  = (float*)(smem + 112640); // [32]

  const int t = threadIdx.x;
  const int l = t & 63, w = t >> 6;
  const int cl = l & 15, g = l >> 4;
  const int r0 = blockIdx.x * 32;
  const int i1 = w >> 1, j1 = w & 1;     // gemm1 wave frag (row16, col16)

  // ---- stage x: [32][256] f32 -> hi/lo LDS ----
  {
    const int srow = t >> 3, q = t & 7;
    const float* src = &X[(size_t)(r0 + srow) * 256];
#pragma unroll
    for (int i = 0; i < 8; ++i) {
      const float4 v = *reinterpret_cast<const float4*>(&src[(q * 8 + i) * 4]);
      const unsigned short h0 = f2bf(v.x), h1 = f2bf(v.y), h2 = f2bf(v.z), h3 = f2bf(v.w);
      uint2 hp, lp;
      hp.x = (unsigned)h0 | ((unsigned)h1 << 16);
      hp.y = (unsigned)h2 | ((unsigned)h3 << 16);
      lp.x = (unsigned)f2bf(v.x - bf2f(h0)) | ((unsigned)f2bf(v.y - bf2f(h1)) << 16);
      lp.y = (unsigned)f2bf(v.z - bf2f(h2)) | ((unsigned)f2bf(v.w - bf2f(h3)) << 16);
      const unsigned byte = AXB(srow, (q * 8 + i) * 8);
      *reinterpret_cast<uint2*>(XH_ + byte) = hp;
      *reinterpret_cast<uint2*>(XL_ + byte) = lp;
    }
  }
  __syncthreads();

  f32x4 oacc[2][4] = {};   // out[32 x 256]: wave w owns cols [w*64, w*64+64)

  // ---- K-chunk loop: 32 H-cols per chunk ----
  for (int cc = 0; cc < 32; ++cc) {
    const float b1v = pb1[cc * 32 + j1 * 16 + cl];
    // stage B1 chunk: 32 hcols x 256 k, hi/lo, XOR swz
    {
      const int row = t >> 3;
#pragma unroll
      for (int ii = 0; ii < 4; ++ii) {
        const int slot = (t & 7) * 4 + ii;
        const uint4 vh = *reinterpret_cast<const uint4*>(&W1Th[(size_t)(cc * 32 + row) * 256 + slot * 8]);
        const uint4 vl = *reinterpret_cast<const uint4*>(&W1Tl[(size_t)(cc * 32 + row) * 256 + slot * 8]);
        const unsigned byte = AXB(row, slot * 16);
        *reinterpret_cast<uint4*>(B1H_ + byte) = vh;
        *reinterpret_cast<uint4*>(B1L_ + byte) = vl;
      }
    }
    // stage B2 chunk: 256 cols x 32 k, pitch 40
#pragma unroll
    for (int s = 0; s < 4; ++s) {
      const uint4 vh = *reinterpret_cast<const uint4*>(&W2Th[(size_t)t * 1024 + cc * 32 + s * 8]);
      const uint4 vl = *reinterpret_cast<const uint4*>(&W2Tl[(size_t)t * 1024 + cc * 32 + s * 8]);
      *reinterpret_cast<uint4*>(B2H_ + t * 80 + s * 16) = vh;
      *reinterpret_cast<uint4*>(B2L_ + t * 80 + s * 16) = vl;
    }
    __syncthreads();

    // gemm1: Hc[32x32] = Xs @ B1 ; wave frag (i1,j1); two chains for ILP
    f32x4 hA = {}, hB = {};
#pragma unroll
    for (int ks = 0; ks < 8; ks += 2) {
      const unsigned cb0 = (unsigned)((ks * 32 + g * 8) * 2);
      const unsigned cb1 = (unsigned)(((ks + 1) * 32 + g * 8) * 2);
      const unsigned a0 = AXB(i1 * 16 + cl, cb0), a1 = AXB(i1 * 16 + cl, cb1);
      const unsigned b0 = AXB(j1 * 16 + cl, cb0), b1b = AXB(j1 * 16 + cl, cb1);
      const bf16x8 ah0 = *(const bf16x8*)(XH_ + a0), al0 = *(const bf16x8*)(XL_ + a0);
      const bf16x8 ah1 = *(const bf16x8*)(XH_ + a1), al1 = *(const bf16x8*)(XL_ + a1);
      const bf16x8 bh0 = *(const bf16x8*)(B1H_ + b0), bl0 = *(const bf16x8*)(B1L_ + b0);
      const bf16x8 bh1 = *(const bf16x8*)(B1H_ + b1b), bl1 = *(const bf16x8*)(B1L_ + b1b);
      hA = MFMA(ah0, bh0, hA, 0, 0, 0);
      hA = MFMA(ah0, bl0, hA, 0, 0, 0);
      hA = MFMA(al0, bh0, hA, 0, 0, 0);
      hB = MFMA(ah1, bh1, hB, 0, 0, 0);
      hB = MFMA(ah1, bl1, hB, 0, 0, 0);
      hB = MFMA(al1, bh1, hB, 0, 0, 0);
    }
    // tanh + split -> Hc LDS
#pragma unroll
    for (int r = 0; r < 4; ++r) {
      const float hv = tanh_fast(hA[r] + hB[r] + b1v);
      const unsigned short hh = f2bf(hv);
      const int sample = i1 * 16 + g * 4 + r, hcol = j1 * 16 + cl;
      *reinterpret_cast<unsigned short*>(HCH_ + sample * 80 + hcol * 2) = hh;
      *reinterpret_cast<unsigned short*>(HCL_ + sample * 80 + hcol * 2) = f2bf(hv - bf2f(hh));
    }
    __syncthreads();

    // gemm2 accumulate: oacc += Hc @ B2 (K=32, 1 k-step)
    bf16x8 a2h[2], a2l[2];
#pragma unroll
    for (int i = 0; i < 2; ++i) {
      const unsigned byte = (unsigned)((i * 16 + cl) * 80 + g * 16);
      a2h[i] = *(const bf16x8*)(HCH_ + byte);
      a2l[i] = *(const bf16x8*)(HCL_ + byte);
    }
#pragma unroll
    for (int j = 0; j < 4; ++j) {
      const unsigned byte = (unsigned)((w * 64 + j * 16 + cl) * 80 + g * 16);
      const bf16x8 b2h = *(const bf16x8*)(B2H_ + byte);
      const bf16x8 b2l = *(const bf16x8*)(B2L_ + byte);
#pragma unroll
      for (int i = 0; i < 2; ++i) {
        oacc[i][j] = MFMA(a2h[i], b2h, oacc[i][j], 0, 0, 0);
        oacc[i][j] = MFMA(a2h[i], b2l, oacc[i][j], 0, 0, 0);
        oacc[i][j] = MFMA(a2l[i], b2h, oacc[i][j], 0, 0, 0);
      }
    }
    __syncthreads();
  }

  // ---- epilogue: f = oacc + b2 + x ; write f hi/lo into B1 area (now FH/FL) ----
  float b2v[4];
#pragma unroll
  for (int j = 0; j < 4; ++j) b2v[j] = pb2[w * 64 + j * 16 + cl];
#pragma unroll
  for (int i = 0; i < 2; ++i)
#pragma unroll
    for (int j = 0; j < 4; ++j)
#pragma unroll
      for (int r = 0; r < 4; ++r) {
        const int row = i * 16 + g * 4 + r, col = w * 64 + j * 16 + cl;
        const unsigned xb = AXB(row, col * 2);
        const float xv = bf2f(*reinterpret_cast<unsigned short*>(XH_ + xb)) +
                         bf2f(*reinterpret_cast<unsigned short*>(XL_ + xb));
        const float f = oacc[i][j][r] + b2v[j] + xv;
        oacc[i][j][r] = f;
        const unsigned short fh = f2bf(f);
        *reinterpret_cast<unsigned short*>(B1H_ + xb) = fh;
        *reinterpret_cast<unsigned short*>(B1L_ + xb) = f2bf(f - bf2f(fh));
      }
  __syncthreads();

  // ---- V phase: Zx = x@Wv, Zf = f@Wv; square-accumulate ----
  float vx_[2][4] = {}, vf_[2][4] = {};
#pragma unroll
  for (int pp = 0; pp < 2; ++pp) {
    bf16x8 wvh[2][8], wvl[2][8];
#pragma unroll
    for (int jj = 0; jj < 2; ++jj)
#pragma unroll
      for (int ks = 0; ks < 8; ++ks) {
        const int col = w * 64 + (pp * 2 + jj) * 16 + cl;
        wvh[jj][ks] = *reinterpret_cast<const bf16x8*>(&WvTh[(size_t)col * 256 + ks * 32 + g * 8]);
        wvl[jj][ks] = *reinterpret_cast<const bf16x8*>(&WvTl[(size_t)col * 256 + ks * 32 + g * 8]);
      }
#pragma unroll
    for (int i = 0; i < 2; ++i)
#pragma unroll
      for (int jj = 0; jj < 2; ++jj) {
        f32x4 zx = {}, zf = {};
#pragma unroll
        for (int ks = 0; ks < 8; ++ks) {
          const unsigned ab = AXB(i * 16 + cl, (ks * 32 + g * 8) * 2);
          const bf16x8 axh = *(const bf16x8*)(XH_ + ab), axl = *(const bf16x8*)(XL_ + ab);
          const bf16x8 afh = *(const bf16x8*)(B1H_ + ab), afl = *(const bf16x8*)(B1L_ + ab);
          zx = MFMA(axh, wvh[jj][ks], zx, 0, 0, 0);
          zx = MFMA(axh, wvl[jj][ks], zx, 0, 0, 0);
          zx = MFMA(axl, wvh[jj][ks], zx, 0, 0, 0);
          zf = MFMA(afh, wvh[jj][ks], zf, 0, 0, 0);
          zf = MFMA(afh, wvl[jj][ks], zf, 0, 0, 0);
          zf = MFMA(afl, wvh[jj][ks], zf, 0, 0, 0);
        }
#pragma unroll
        for (int r = 0; r < 4; ++r) {
          vx_[i][r] = fmaf(zx[r], zx[r], vx_[i][r]);
          vf_[i][r] = fmaf(zf[r], zf[r], vf_[i][r]);
        }
      }
  }
  // reduce over the 16 Z-col lanes
#pragma unroll
  for (int i = 0; i < 2; ++i)
#pragma unroll
    for (int r = 0; r < 4; ++r) {
      float a = vx_[i][r], b = vf_[i][r];
      a += __shfl_xor(a, 1); a += __shfl_xor(a, 2); a += __shfl_xor(a, 4); a += __shfl_xor(a, 8);
      b += __shfl_xor(b, 1); b += __shfl_xor(b, 2); b += __shfl_xor(b, 4); b += __shfl_xor(b, 8);
      if (cl == 0) {
        const int row = i * 16 + g * 4 + r;
        PART[(0 * 32 + row) * 4 + w] = a;
        PART[(1 * 32 + row) * 4 + w] = b;
      }
    }
  __syncthreads();

  if (t < 32) {
    float Vx = 0.f, Vf = 0.f;
#pragma unroll
    for (int i = 0; i < 4; ++i) { Vx += PART[(t) * 4 + i]; Vf += PART[(32 + t) * 4 + i]; }
    const float tt2 = 0.99f * Vx;
    float a;
    if (Vf - tt2 > 0.0f)        a = sqrtf(tt2 / Vf);   // Newton limit
    else if (tt2 - Vf > 1e-4f)  a = 0.5f;              // stuck-bisection case
    else                        a = 1.0f;              // never masked
    ALS[t] = a;
  }
  __syncthreads();

  // ---- scaled store ----
#pragma unroll
  for (int i = 0; i < 2; ++i)
#pragma unroll
    for (int r = 0; r < 4; ++r) {
      const int row = i * 16 + g * 4 + r;
      const float a = ALS[row];
#pragma unroll
      for (int j = 0; j < 4; ++j) {
        const int col = w * 64 + j * 16 + cl;
        OUT[(size_t)(r0 + row) * 256 + col] = oacc[i][j][r] * a;
      }
    }
}

extern "C" void kernel_launch(void* const* d_in, const int* in_sizes, int n_in,
                              void* d_out, int out_size, void* d_ws, size_t ws_size,
                              hipStream_t stream) {
  const float* x  = (const float*)d_in[0];
  const float* W1 = (const float*)d_in[1];
  const float* b1 = (const float*)d_in[2];
  const float* W2 = (const float*)d_in[3];
  const float* b2 = (const float*)d_in[4];
  const float* Wv = (const float*)d_in[5];
  float* out = (float*)d_out;

  char* ws = (char*)d_ws;
  unsigned short* W1Th = (unsigned short*)(ws);
  unsigned short* W1Tl = (unsigned short*)(ws + 524288);
  unsigned short* W2Th = (unsigned short*)(ws + 1048576);
  unsigned short* W2Tl = (unsigned short*)(ws + 1572864);
  unsigned short* WvTh = (unsigned short*)(ws + 2097152);
  unsigned short* WvTl = (unsigned short*)(ws + 2228224);

  k_split<<<dim3(144), dim3(256), 0, stream>>>(W1, W2, Wv, W1Th, W1Tl, W2Th, W2Tl, WvTh, WvTl);
  k_fused<<<dim3(256), dim3(256), 0, stream>>>(x, b1, b2, W1Th, W1Tl, W2Th, W2Tl, WvTh, WvTl, out);
}

// Round 8
// 84.144 us; speedup vs baseline: 1.3733x; 1.3733x over previous
//
#include <hip/hip_runtime.h>
#include <math.h>

typedef __attribute__((ext_vector_type(8))) short bf16x8;
typedef __attribute__((ext_vector_type(4))) float f32x4;

#define MFMA __builtin_amdgcn_mfma_f32_16x16x32_bf16

static __device__ __forceinline__ unsigned short f2bf(float f) {
  union { float f; unsigned u; } a; a.f = f;
  unsigned u = a.u;
  unsigned r = u + 0x7FFF + ((u >> 16) & 1);   // RNE
  return (unsigned short)(r >> 16);
}
static __device__ __forceinline__ float bf2f(unsigned short h) {
  union { unsigned u; float f; } a; a.u = ((unsigned)h) << 16;
  return a.f;
}
static __device__ __forceinline__ float tanh_fast(float x) {
  float ax = fabsf(x);
  float e = __expf(-2.0f * ax);
  float t = (1.0f - e) / (1.0f + e);
  t = (ax > 10.0f) ? 1.0f : t;
  return (x < 0.0f) ? -t : t;
}
static __device__ __forceinline__ void gload16(const void* g, void* l) {
  __builtin_amdgcn_global_load_lds(
      (const __attribute__((address_space(1))) unsigned int*)g,
      (__attribute__((address_space(3))) unsigned int*)l, 16, 0, 0);
}

// swizzles: 512B-row planes (B1/F/X) and 64B-row Hc plane
#define SWZ512(row) ((((unsigned)(row)) & 7u) << 4)
#define SWZHC(row)  (((((unsigned)(row)) ^ (((unsigned)(row)) >> 2)) & 3u) << 4)

// Weight transpose+split (verified r6/r7 code).
__global__ __launch_bounds__(256) void k_split(
    const float* __restrict__ W1, const float* __restrict__ W2, const float* __restrict__ Wv,
    unsigned short* __restrict__ W1Th, unsigned short* __restrict__ W1Tl,
    unsigned short* __restrict__ W2Th, unsigned short* __restrict__ W2Tl,
    unsigned short* __restrict__ WvTh, unsigned short* __restrict__ WvTl)
{
  const int b = blockIdx.x, t = threadIdx.x;
  __shared__ unsigned short shh[64 * 72], shl[64 * 72];
  const float* W; unsigned short *Th, *Tl; int Kd, Nd, k0, n0;
  if (b < 64)       { W = W1; Th = W1Th; Tl = W1Tl; Kd = 256;  Nd = 1024; k0 = (b & 3) * 64;         n0 = (b >> 2) * 64; }
  else if (b < 128) { W = W2; Th = W2Th; Tl = W2Tl; Kd = 1024; Nd = 256;  k0 = ((b - 64) & 15) * 64; n0 = ((b - 64) >> 4) * 64; }
  else              { W = Wv; Th = WvTh; Tl = WvTl; Kd = 256;  Nd = 256;  k0 = ((b - 128) & 3) * 64; n0 = ((b - 128) >> 2) * 64; }

  const int kloc = t >> 4, n4 = t & 15;
#pragma unroll
  for (int p = 0; p < 4; ++p) {
    const int kk = p * 16 + kloc;
    const float4 v = *reinterpret_cast<const float4*>(&W[(size_t)(k0 + kk) * Nd + n0 + n4 * 4]);
    const float vv[4] = {v.x, v.y, v.z, v.w};
#pragma unroll
    for (int e = 0; e < 4; ++e) {
      const unsigned short hh = f2bf(vv[e]);
      shh[(n4 * 4 + e) * 72 + kk] = hh;
      shl[(n4 * 4 + e) * 72 + kk] = f2bf(vv[e] - bf2f(hh));
    }
  }
  __syncthreads();
  const int nl = t >> 2, ko = (t & 3) * 16;
  const size_t dst = (size_t)(n0 + nl) * Kd + k0 + ko;
  *reinterpret_cast<uint4*>(&Th[dst])     = *reinterpret_cast<const uint4*>(&shh[nl * 72 + ko]);
  *reinterpret_cast<uint4*>(&Th[dst + 8]) = *reinterpret_cast<const uint4*>(&shh[nl * 72 + ko + 8]);
  *reinterpret_cast<uint4*>(&Tl[dst])     = *reinterpret_cast<const uint4*>(&shl[nl * 72 + ko]);
  *reinterpret_cast<uint4*>(&Tl[dst + 8]) = *reinterpret_cast<const uint4*>(&shl[nl * 72 + ko + 8]);
}

// LDS map (bytes):
//   0      B1 buf0:  H 16K | L 16K   (after K-loop: FH 16K | FL 16K)
//   32768  B1 buf1:  H 16K | L 16K   (after K-loop: XH 16K | XL 16K)
//   65536  HC buf0: H 2K | L 2K ; 69632 HC buf1
//   73728  PARTX 1K | PARTF 1K ; 75776 ALS 128B
__global__ __launch_bounds__(512, 2) void k_fused(
    const float* __restrict__ X, const float* __restrict__ pb1, const float* __restrict__ pb2,
    const unsigned short* __restrict__ W1Th, const unsigned short* __restrict__ W1Tl,
    const unsigned short* __restrict__ W2Th, const unsigned short* __restrict__ W2Tl,
    const unsigned short* __restrict__ WvTh, const unsigned short* __restrict__ WvTl,
    float* __restrict__ OUT)
{
  __shared__ __align__(16) unsigned char smem[76032];
  const int t = threadIdx.x;
  const int l = t & 63, w = t >> 6;
  const int cl = l & 15, g = l >> 4;
  const int r0 = blockIdx.x * 32;
  // g1 = waves 0..3 (producers), g2 = waves 4..7 (consumers)
  const int i1 = w & 1, j1 = (w >> 1) & 1;   // g1 frag coords
  const int u  = w - 4;                       // g2 col-block (0..3)

  // ---- g1: X fragments -> registers (once) ----
  bf16x8 xh[8], xl[8];
  if (w < 4) {
    const int row = i1 * 16 + cl;
    const float* xs = &X[(size_t)(r0 + row) * 256];
#pragma unroll
    for (int ks = 0; ks < 8; ++ks) {
      const float4 v0 = *reinterpret_cast<const float4*>(&xs[ks * 32 + g * 8]);
      const float4 v1 = *reinterpret_cast<const float4*>(&xs[ks * 32 + g * 8 + 4]);
      const float vv[8] = {v0.x, v0.y, v0.z, v0.w, v1.x, v1.y, v1.z, v1.w};
      union { bf16x8 v; unsigned short s[8]; } uh, ul;
#pragma unroll
      for (int e = 0; e < 8; ++e) {
        uh.s[e] = f2bf(vv[e]);
        ul.s[e] = f2bf(vv[e] - bf2f(uh.s[e]));
      }
      xh[ks] = uh.v; xl[ks] = ul.v;
    }
  }

  // ---- B1 prefetch via global_load_lds: chunk cc -> buf[cc&1] ----
  // layout [32 hcol][512B] with byte = row*512 + (o ^ SWZ512(row))
  auto issue_b1 = [&](int cc, int buf) {
    const unsigned short* wp = (w & 2) ? W1Tl : W1Th;   // waves 0,1: H; 2,3: L
    unsigned char* base = smem + buf * 32768 + ((w & 2) ? 16384 : 0);
#pragma unroll
    for (int s = 0; s < 8; ++s) {
      const int c1k = (w & 1) * 8 + s;
      const int row = c1k * 2 + (l >> 5);
      const unsigned o = (unsigned)((l & 31) * 16) ^ SWZ512(row);
      gload16(wp + (size_t)(cc * 32 + row) * 256 + (o >> 1), base + c1k * 1024);
    }
  };

  if (w < 4) issue_b1(0, 0);
  __syncthreads();

  f32x4 oacc[2][4] = {};   // g2: rows 32, cols u*64..u*64+63

  for (int cc = 0; cc <= 32; ++cc) {
    if (cc < 31 && w < 4) issue_b1(cc + 1, (cc + 1) & 1);

    if (cc < 32 && w < 4) {
      // ---- gemm1(cc): Hc[32][32] frag (i1,j1), operands B1 from LDS, X from regs ----
      const unsigned char* B1 = smem + (cc & 1) * 32768;
      const int col = j1 * 16 + cl;
      const float b1v = pb1[cc * 32 + col];
      f32x4 hA = {}, hB = {};
#pragma unroll
      for (int ks = 0; ks < 8; ks += 2) {
        const unsigned b0 = col * 512 + ((unsigned)(ks * 64 + g * 16) ^ SWZ512(col));
        const unsigned b1b = col * 512 + ((unsigned)((ks + 1) * 64 + g * 16) ^ SWZ512(col));
        const bf16x8 bh0 = *(const bf16x8*)(B1 + b0);
        const bf16x8 bl0 = *(const bf16x8*)(B1 + 16384 + b0);
        const bf16x8 bh1 = *(const bf16x8*)(B1 + b1b);
        const bf16x8 bl1 = *(const bf16x8*)(B1 + 16384 + b1b);
        hA = MFMA(xh[ks], bh0, hA, 0, 0, 0);
        hA = MFMA(xh[ks], bl0, hA, 0, 0, 0);
        hA = MFMA(xl[ks], bh0, hA, 0, 0, 0);
        hB = MFMA(xh[ks + 1], bh1, hB, 0, 0, 0);
        hB = MFMA(xh[ks + 1], bl1, hB, 0, 0, 0);
        hB = MFMA(xl[ks + 1], bh1, hB, 0, 0, 0);
      }
      unsigned char* HC = smem + 65536 + (cc & 1) * 4096;
#pragma unroll
      for (int r = 0; r < 4; ++r) {
        const int samp = i1 * 16 + g * 4 + r;
        const float hv = tanh_fast(hA[r] + hB[r] + b1v);
        const unsigned short hh = f2bf(hv);
        const unsigned byte = samp * 64 + ((unsigned)(col * 2) ^ SWZHC(samp));
        *reinterpret_cast<unsigned short*>(HC + byte) = hh;
        *reinterpret_cast<unsigned short*>(HC + 2048 + byte) = f2bf(hv - bf2f(hh));
      }
    }

    if (cc >= 1 && w >= 4) {
      // ---- gemm2(cc-1): oacc += Hc @ W2-slice; B2 frags straight from L2 ----
      const int c2 = cc - 1;
      bf16x8 b2h[4], b2l[4];
#pragma unroll
      for (int j = 0; j < 4; ++j) {
        const size_t off = (size_t)(u * 64 + j * 16 + cl) * 1024 + c2 * 32 + g * 8;
        b2h[j] = *reinterpret_cast<const bf16x8*>(&W2Th[off]);
        b2l[j] = *reinterpret_cast<const bf16x8*>(&W2Tl[off]);
      }
      const unsigned char* HC = smem + 65536 + (c2 & 1) * 4096;
      bf16x8 a2h[2], a2l[2];
#pragma unroll
      for (int i = 0; i < 2; ++i) {
        const int row = i * 16 + cl;
        const unsigned byte = row * 64 + ((unsigned)(g * 16) ^ SWZHC(row));
        a2h[i] = *(const bf16x8*)(HC + byte);
        a2l[i] = *(const bf16x8*)(HC + 2048 + byte);
      }
#pragma unroll
      for (int i = 0; i < 2; ++i)
#pragma unroll
        for (int j = 0; j < 4; ++j) {
          oacc[i][j] = MFMA(a2h[i], b2h[j], oacc[i][j], 0, 0, 0);
          oacc[i][j] = MFMA(a2h[i], b2l[j], oacc[i][j], 0, 0, 0);
          oacc[i][j] = MFMA(a2l[i], b2h[j], oacc[i][j], 0, 0, 0);
        }
    }
    __syncthreads();
  }

  // ---- epilogue: X frags -> LDS (buf1 area); f = oacc+b2+x -> F planes (buf0) ----
  if (w < 2) {   // j1==0 waves cover both i-halves
    const int row = i1 * 16 + cl;
#pragma unroll
    for (int ks = 0; ks < 8; ++ks) {
      const unsigned byte = 32768 + row * 512 + ((unsigned)(ks * 64 + g * 16) ^ SWZ512(row));
      *reinterpret_cast<bf16x8*>(smem + byte) = xh[ks];
      *reinterpret_cast<bf16x8*>(smem + 16384 + byte) = xl[ks];
    }
  }
  if (w >= 4) {
    float b2v[4];
#pragma unroll
    for (int j = 0; j < 4; ++j) b2v[j] = pb2[u * 64 + j * 16 + cl];
#pragma unroll
    for (int i = 0; i < 2; ++i)
#pragma unroll
      for (int j = 0; j < 4; ++j)
#pragma unroll
        for (int r = 0; r < 4; ++r) {
          const int row = i * 16 + g * 4 + r;
          const int col = u * 64 + j * 16 + cl;
          const float xv = X[(size_t)(r0 + row) * 256 + col];
          const float f = oacc[i][j][r] + b2v[j] + xv;
          oacc[i][j][r] = f;
          const unsigned short fh = f2bf(f);
          const unsigned byte = row * 512 + ((unsigned)(col * 2) ^ SWZ512(row));
          *reinterpret_cast<unsigned short*>(smem + byte) = fh;
          *reinterpret_cast<unsigned short*>(smem + 16384 + byte) = f2bf(f - bf2f(fh));
        }
  }
  __syncthreads();

  // ---- V phase (all 8 waves): wave owns 32 Wv cols; Wv frags from L2 ----
  {
    bf16x8 wvh[2][8], wvl[2][8];
#pragma unroll
    for (int nf = 0; nf < 2; ++nf)
#pragma unroll
      for (int ks = 0; ks < 8; ++ks) {
        const size_t off = (size_t)(w * 32 + nf * 16 + cl) * 256 + ks * 32 + g * 8;
        wvh[nf][ks] = *reinterpret_cast<const bf16x8*>(&WvTh[off]);
        wvl[nf][ks] = *reinterpret_cast<const bf16x8*>(&WvTl[off]);
      }
    float vx_[2][4] = {}, vf_[2][4] = {};
#pragma unroll
    for (int i = 0; i < 2; ++i) {
      f32x4 zx[2] = {}, zf[2] = {};
#pragma unroll
      for (int ks = 0; ks < 8; ++ks) {
        const int row = i * 16 + cl;
        const unsigned byte = row * 512 + ((unsigned)(ks * 64 + g * 16) ^ SWZ512(row));
        const bf16x8 fhv = *(const bf16x8*)(smem + byte);
        const bf16x8 flv = *(const bf16x8*)(smem + 16384 + byte);
        const bf16x8 xhv = *(const bf16x8*)(smem + 32768 + byte);
        const bf16x8 xlv = *(const bf16x8*)(smem + 49152 + byte);
#pragma unroll
        for (int nf = 0; nf < 2; ++nf) {
          zx[nf] = MFMA(xhv, wvh[nf][ks], zx[nf], 0, 0, 0);
          zx[nf] = MFMA(xhv, wvl[nf][ks], zx[nf], 0, 0, 0);
          zx[nf] = MFMA(xlv, wvh[nf][ks], zx[nf], 0, 0, 0);
          zf[nf] = MFMA(fhv, wvh[nf][ks], zf[nf], 0, 0, 0);
          zf[nf] = MFMA(fhv, wvl[nf][ks], zf[nf], 0, 0, 0);
          zf[nf] = MFMA(flv, wvh[nf][ks], zf[nf], 0, 0, 0);
        }
      }
#pragma unroll
      for (int nf = 0; nf < 2; ++nf)
#pragma unroll
        for (int r = 0; r < 4; ++r) {
          vx_[i][r] = fmaf(zx[nf][r], zx[nf][r], vx_[i][r]);
          vf_[i][r] = fmaf(zf[nf][r], zf[nf][r], vf_[i][r]);
        }
    }
    float* PX = (float*)(smem + 73728);
    float* PF = (float*)(smem + 74752);
#pragma unroll
    for (int i = 0; i < 2; ++i)
#pragma unroll
      for (int r = 0; r < 4; ++r) {
        float a = vx_[i][r], b = vf_[i][r];
        a += __shfl_xor(a, 1); a += __shfl_xor(a, 2); a += __shfl_xor(a, 4); a += __shfl_xor(a, 8);
        b += __shfl_xor(b, 1); b += __shfl_xor(b, 2); b += __shfl_xor(b, 4); b += __shfl_xor(b, 8);
        if (cl == 0) {
          const int row = i * 16 + g * 4 + r;
          PX[row * 8 + w] = a;
          PF[row * 8 + w] = b;
        }
      }
  }
  __syncthreads();

  float* ALS = (float*)(smem + 75776);
  if (t < 32) {
    const float* PX = (const float*)(smem + 73728);
    const float* PF = (const float*)(smem + 74752);
    float Vx = 0.f, Vf = 0.f;
#pragma unroll
    for (int i = 0; i < 8; ++i) { Vx += PX[t * 8 + i]; Vf += PF[t * 8 + i]; }
    const float tt2 = 0.99f * Vx;
    float a;
    if (Vf - tt2 > 0.0f)        a = sqrtf(tt2 / Vf);   // Newton limit
    else if (tt2 - Vf > 1e-4f)  a = 0.5f;              // stuck-bisection case
    else                        a = 1.0f;              // never masked
    ALS[t] = a;
  }
  __syncthreads();

  if (w >= 4) {
#pragma unroll
    for (int i = 0; i < 2; ++i)
#pragma unroll
      for (int r = 0; r < 4; ++r) {
        const int row = i * 16 + g * 4 + r;
        const float a = ALS[row];
#pragma unroll
        for (int j = 0; j < 4; ++j) {
          const int col = u * 64 + j * 16 + cl;
          OUT[(size_t)(r0 + row) * 256 + col] = oacc[i][j][r] * a;
        }
      }
  }
}

extern "C" void kernel_launch(void* const* d_in, const int* in_sizes, int n_in,
                              void* d_out, int out_size, void* d_ws, size_t ws_size,
                              hipStream_t stream) {
  const float* x  = (const float*)d_in[0];
  const float* W1 = (const float*)d_in[1];
  const float* b1 = (const float*)d_in[2];
  const float* W2 = (const float*)d_in[3];
  const float* b2 = (const float*)d_in[4];
  const float* Wv = (const float*)d_in[5];
  float* out = (float*)d_out;

  char* ws = (char*)d_ws;
  unsigned short* W1Th = (unsigned short*)(ws);
  unsigned short* W1Tl = (unsigned short*)(ws + 524288);
  unsigned short* W2Th = (unsigned short*)(ws + 1048576);
  unsigned short* W2Tl = (unsigned short*)(ws + 1572864);
  unsigned short* WvTh = (unsigned short*)(ws + 2097152);
  unsigned short* WvTl = (unsigned short*)(ws + 2228224);

  k_split<<<dim3(144), dim3(256), 0, stream>>>(W1, W2, Wv, W1Th, W1Tl, W2Th, W2Tl, WvTh, WvTl);
  k_fused<<<dim3(256), dim3(512), 0, stream>>>(x, b1, b2, W1Th, W1Tl, W2Th, W2Tl, WvTh, WvTl, out);
}